// Round 7
// baseline (295.078 us; speedup 1.0000x reference)
//
#include <hip/hip_runtime.h>
#include <math.h>

// Problem constants (fixed by setup_inputs)
constexpr int NB = 64;     // batch
constexpr int NT = 1024;   // time steps
constexpr int NV = 256;    // vocab
constexpr int NS = 256;    // target length (padded)
constexpr int NL = 2 * NS + 1;        // 513 extended CTC states
constexpr int NDG = NT + NS - 1;      // 1279 anti-diagonals
__device__ constexpr float BIGV = 1e10f;

using f32x4 = __attribute__((ext_vector_type(4))) float;
using s16x8 = __attribute__((ext_vector_type(8))) short;

// ---------------- DPP cross-lane helpers ----------------
__device__ __forceinline__ float dpp_shr1_f32(float x, float lane0val) {
    int r = __builtin_amdgcn_update_dpp(__float_as_int(lane0val),
                                        __float_as_int(x), 0x138, 0xf, 0xf, false);
    return __int_as_float(r);
}
__device__ __forceinline__ double dpp_shr1_zero_f64(double x) {
    union { double d; unsigned long long u; } c; c.d = x;
    int lo = (int)(c.u & 0xffffffffull), hi = (int)(c.u >> 32);
    int nlo = __builtin_amdgcn_update_dpp(0, lo, 0x138, 0xf, 0xf, true);
    int nhi = __builtin_amdgcn_update_dpp(0, hi, 0x138, 0xf, 0xf, true);
    c.u = ((unsigned long long)(unsigned)nhi << 32) | (unsigned)nlo;
    return c.d;
}
__device__ __forceinline__ int wave_imax_dpp(int x) {
    int t;
    t = __builtin_amdgcn_update_dpp(0, x, 0x111, 0xf, 0xf, true); x = max(x, t);
    t = __builtin_amdgcn_update_dpp(0, x, 0x112, 0xf, 0xf, true); x = max(x, t);
    t = __builtin_amdgcn_update_dpp(0, x, 0x114, 0xf, 0xf, true); x = max(x, t);
    t = __builtin_amdgcn_update_dpp(0, x, 0x118, 0xf, 0xf, true); x = max(x, t);
    t = __builtin_amdgcn_update_dpp(0, x, 0x142, 0xf, 0xf, true); x = max(x, t);
    t = __builtin_amdgcn_update_dpp(0, x, 0x143, 0xf, 0xf, true); x = max(x, t);
    return __builtin_amdgcn_readlane(x, 63);
}
// sum over the 16-lane DPP row; result valid in lane (row's) 15
__device__ __forceinline__ float row16_sum(float x) {
    x += __int_as_float(__builtin_amdgcn_update_dpp(0, __float_as_int(x), 0x111, 0xf, 0xf, true));
    x += __int_as_float(__builtin_amdgcn_update_dpp(0, __float_as_int(x), 0x112, 0xf, 0xf, true));
    x += __int_as_float(__builtin_amdgcn_update_dpp(0, __float_as_int(x), 0x114, 0xf, 0xf, true));
    x += __int_as_float(__builtin_amdgcn_update_dpp(0, __float_as_int(x), 0x118, 0xf, 0xf, true));
    return x;
}
__device__ __forceinline__ unsigned short f2bf(float x) {   // round-to-nearest-even
    unsigned u = __float_as_uint(x);
    return (unsigned short)((u + 0x7fffu + ((u >> 16) & 1u)) >> 16);
}

// ---------------------------------------------------------------------------
// K1 (MFMA rewrite): per block = 128 rows of one batch.
//   E  = bf16(exp(lp tile))          (LDS, GEMM1 A)
//   pred = E @ F        (MFMA, K=256, N=32 padded from 24)
//   dot  = pred @ tgf^T (MFMA, K=32 padded from 24)
//   D = predsq[a] + tsq[j] - 2*dot  -> staged in LDS -> coalesced diag scatter
// Also emits Gbf (bf16 gathered CTC probs) + PB (blank prob column).
// ---------------------------------------------------------------------------
__global__ __launch_bounds__(256) void k_dmat(
    const float* __restrict__ lp, const float* __restrict__ fm,
    const int* __restrict__ tgt, float* __restrict__ Ddiag,
    unsigned short* __restrict__ Gbf, float* __restrict__ PB)
{
    constexpr int ESTR = 264;   // E stride (elems); 528B rows, 16B aligned
    constexpr int FSTR = 264;   // FT stride
    constexpr int TSTR = 40;    // tgf stride (80B rows)
    constexpr int PSTR = 40;    // predb16 stride
    constexpr int DSTR = 130;   // Dst stride (dwords)

    __shared__ __align__(16) unsigned char uni[128 * ESTR * 2];  // E / Dst union
    __shared__ __align__(16) unsigned short FT[32 * FSTR];       // F^T bf16 (pad n>=24 zero)
    __shared__ __align__(16) unsigned short tgf[256 * TSTR];     // target feats bf16
    __shared__ __align__(16) unsigned short pb16[128 * PSTR];    // pred bf16
    __shared__ float tsq[256];
    __shared__ float psq[128];

    unsigned short* E = (unsigned short*)uni;
    float* Dst = (float*)uni;

    const int tid  = threadIdx.x;
    const int lane = tid & 63;
    const int w    = tid >> 6;
    const int b    = blockIdx.x >> 3;
    const int a0   = (blockIdx.x & 7) * 128;

    // ---- stage FT[n][v] = bf16(fm[v][n]) (thread = v) ----
    {
        const float* fr = fm + tid * 24;
        #pragma unroll
        for (int k = 0; k < 24; k += 4) {
            float4 t4 = *(const float4*)(fr + k);
            FT[(k + 0) * FSTR + tid] = f2bf(t4.x);
            FT[(k + 1) * FSTR + tid] = f2bf(t4.y);
            FT[(k + 2) * FSTR + tid] = f2bf(t4.z);
            FT[(k + 3) * FSTR + tid] = f2bf(t4.w);
        }
        #pragma unroll
        for (int n = 24; n < 32; ++n) FT[n * FSTR + tid] = 0;
    }
    // ---- stage tgf[j][k] + tsq[j] (thread = j) ----
    const int lab = tgt[b * NS + tid];
    {
        const float* fr = fm + lab * 24;
        float s = 0.f;
        #pragma unroll
        for (int k = 0; k < 24; k += 4) {
            float4 t4 = *(const float4*)(fr + k);
            unsigned p0 = f2bf(t4.x) | ((unsigned)f2bf(t4.y) << 16);
            unsigned p1 = f2bf(t4.z) | ((unsigned)f2bf(t4.w) << 16);
            *(unsigned*)&tgf[tid * TSTR + k]     = p0;
            *(unsigned*)&tgf[tid * TSTR + k + 2] = p1;
            s += t4.x * t4.x + t4.y * t4.y + t4.z * t4.z + t4.w * t4.w;
        }
        #pragma unroll
        for (int k = 24; k < 32; k += 2) *(unsigned*)&tgf[tid * TSTR + k] = 0;
        tsq[tid] = s;
    }
    // ---- stage E = bf16(exp(lp)) + PB ----
    {
        const float* src = lp + ((size_t)b * NT + a0) * NV;
        #pragma unroll
        for (int it = 0; it < 32; ++it) {
            int f4  = it * 256 + tid;
            int row = f4 >> 6;
            int c4  = f4 & 63;
            float4 v = *(const float4*)(src + row * NV + c4 * 4);
            float e0 = __expf(v.x), e1 = __expf(v.y);
            float e2 = __expf(v.z), e3 = __expf(v.w);
            unsigned* dst = (unsigned*)&E[row * ESTR + c4 * 4];
            dst[0] = f2bf(e0) | ((unsigned)f2bf(e1) << 16);
            dst[1] = f2bf(e2) | ((unsigned)f2bf(e3) << 16);
            if (c4 == 0) PB[b * NT + a0 + row] = e0;
        }
    }
    __syncthreads();

    // ---- Gbf gather: thread s = tid, 128 rows ----
    {
        unsigned short* gd = Gbf + (((size_t)(b * NT + a0)) << 8) + tid;
        #pragma unroll 4
        for (int r = 0; r < 128; ++r) gd[(size_t)r << 8] = E[r * ESTR + lab];
    }

    // ---- GEMM1: pred(32x32) = E(rows m0..m0+32) @ F ----
    const int m0  = 32 * w;
    const int q   = lane >> 4;
    const int n16 = lane & 15;
    f32x4 acc00 = {0.f, 0.f, 0.f, 0.f}, acc01 = acc00, acc10 = acc00, acc11 = acc00;
    #pragma unroll
    for (int ks = 0; ks < 8; ++ks) {
        s16x8 a0f = *(const s16x8*)&E[(m0 + n16) * ESTR + ks * 32 + q * 8];
        s16x8 a1f = *(const s16x8*)&E[(m0 + 16 + n16) * ESTR + ks * 32 + q * 8];
        s16x8 b0f = *(const s16x8*)&FT[(n16) * FSTR + ks * 32 + q * 8];
        s16x8 b1f = *(const s16x8*)&FT[(16 + n16) * FSTR + ks * 32 + q * 8];
        acc00 = __builtin_amdgcn_mfma_f32_16x16x32_bf16(a0f, b0f, acc00, 0, 0, 0);
        acc01 = __builtin_amdgcn_mfma_f32_16x16x32_bf16(a0f, b1f, acc01, 0, 0, 0);
        acc10 = __builtin_amdgcn_mfma_f32_16x16x32_bf16(a1f, b0f, acc10, 0, 0, 0);
        acc11 = __builtin_amdgcn_mfma_f32_16x16x32_bf16(a1f, b1f, acc11, 0, 0, 0);
    }
    // predsq (fp32, DPP row-reduce) + predb16 writes
    #pragma unroll
    for (int r = 0; r < 4; ++r) {
        float s0 = acc00[r] * acc00[r] + acc01[r] * acc01[r];
        float s1 = acc10[r] * acc10[r] + acc11[r] * acc11[r];
        s0 = row16_sum(s0); s1 = row16_sum(s1);
        if (n16 == 15) {
            psq[m0 + 4 * q + r]      = s0;
            psq[m0 + 16 + 4 * q + r] = s1;
        }
        pb16[(m0 + 4 * q + r) * PSTR + n16]           = f2bf(acc00[r]);
        pb16[(m0 + 4 * q + r) * PSTR + 16 + n16]      = f2bf(acc01[r]);
        pb16[(m0 + 16 + 4 * q + r) * PSTR + n16]      = f2bf(acc10[r]);
        pb16[(m0 + 16 + 4 * q + r) * PSTR + 16 + n16] = f2bf(acc11[r]);
    }

    // ---- per half: GEMM2 (dot = pred @ tgf^T) -> D -> diagonal scatter ----
    #pragma unroll 1
    for (int h = 0; h < 2; ++h) {
        __syncthreads();   // pb16/psq ready; Dst region free (E dead / prev scatter done)
        s16x8 pa0 = *(const s16x8*)&pb16[(m0 + n16) * PSTR + q * 8];
        s16x8 pa1 = *(const s16x8*)&pb16[(m0 + 16 + n16) * PSTR + q * 8];
        float ps0[4], ps1[4];
        #pragma unroll
        for (int r = 0; r < 4; ++r) {
            ps0[r] = psq[m0 + 4 * q + r];
            ps1[r] = psq[m0 + 16 + 4 * q + r];
        }
        #pragma unroll
        for (int nt = 0; nt < 8; ++nt) {
            const int j0 = 16 * nt;                       // within half
            s16x8 tb = *(const s16x8*)&tgf[(128 * h + j0 + n16) * TSTR + q * 8];
            float tq = tsq[128 * h + j0 + n16];
            f32x4 z = {0.f, 0.f, 0.f, 0.f};
            f32x4 d0 = __builtin_amdgcn_mfma_f32_16x16x32_bf16(pa0, tb, z, 0, 0, 0);
            f32x4 d1 = __builtin_amdgcn_mfma_f32_16x16x32_bf16(pa1, tb, z, 0, 0, 0);
            #pragma unroll
            for (int r = 0; r < 4; ++r) {
                Dst[(m0 + 4 * q + r) * DSTR + j0 + n16]      = ps0[r] + tq - 2.f * d0[r];
                Dst[(m0 + 16 + 4 * q + r) * DSTR + j0 + n16] = ps1[r] + tq - 2.f * d1[r];
            }
        }
        __syncthreads();
        // coalesced diagonal scatter of this half
        for (int i = 0; i < 64; ++i) {
            int dp  = 4 * i + w;                           // local diagonal 0..255
            int jlo = dp > 127 ? dp - 127 : 0;
            int jhi = dp < 127 ? dp : 127;
            #pragma unroll
            for (int c = 0; c < 2; ++c) {
                int jj = jlo + 64 * c + lane;
                if (jj <= jhi) {
                    float vv = Dst[(dp - jj) * DSTR + jj];
                    Ddiag[((size_t)b * NDG + a0 + 128 * h + dp) * NS + 128 * h + jj] = vv;
                }
            }
        }
    }
}

// ---------------------------------------------------------------------------
// K2: single-wave DPs; DPP cross-lane; branch-free load streams.
// blocks 0..63:  CTC linear-fp64, depth-24 queue, pow-2 rescale every 8 steps.
// blocks 64..127: SoftDTW hard-min wavefront, depth-32 float4 queue.
// ---------------------------------------------------------------------------
__global__ __launch_bounds__(64) void k_dp(
    const float* __restrict__ lp, const int* __restrict__ tgt,
    const int* __restrict__ ilen, const int* __restrict__ tlen,
    const float* __restrict__ Ddiag, const unsigned short* __restrict__ Gbf,
    const float* __restrict__ PB, float* __restrict__ ctc_out,
    float* __restrict__ sdtw_out)
{
    __shared__ double smd[513];
    const int lane = threadIdx.x;
    const int bid = blockIdx.x;

    if (bid < NB) {
        // ------------------------- CTC, linear fp64 -------------------------
        const int b  = bid;
        const int len = ilen[b];
        const int tl  = tlen[b];
        const float* lpb = lp + (size_t)b * NT * NV;
        const unsigned short* Gb = Gbf + ((size_t)(b * NT) << 8);
        const float* PBb = PB + b * NT;

        const int4 t4 = ((const int4*)(tgt + b * NS))[lane];
        const int prevw = __shfl_up(t4.w, 1);
        const double m1d = ((lane > 0) && (t4.x != prevw)) ? 1.0 : 0.0;
        const double m3d = (t4.y != t4.x) ? 1.0 : 0.0;
        const double m5d = (t4.z != t4.y) ? 1.0 : 0.0;
        const double m7d = (t4.w != t4.z) ? 1.0 : 0.0;

        double a0 = 0.0, a1 = 0.0, a2 = 0.0, a3 = 0.0, a4 = 0.0,
               a5 = 0.0, a6 = 0.0, a7 = 0.0, a8 = 0.0;
        if (lane == 0) {
            a0 = (double)__expf(lpb[0]);
            a1 = (double)__expf(lpb[t4.x]);
        }
        long long Ksum = 0;

        ushort4 gq[24];
        float   pbq[24];
        #pragma unroll
        for (int q = 0; q < 24; ++q) {
            gq[q]  = *(const ushort4*)(Gb + (((size_t)(1 + q)) << 8) + 4 * lane);
            pbq[q] = PBb[1 + q];
        }

        for (int t0 = 1; t0 < len; t0 += 24) {
            #pragma unroll
            for (int u = 0; u < 24; ++u) {
                const int t = t0 + u;
                const ushort4 gu = gq[u];
                const float pbf  = pbq[u];
                int tn = t + 24; if (tn > NT - 1) tn = NT - 1;
                gq[u]  = *(const ushort4*)(Gb + (((size_t)tn) << 8) + 4 * lane);
                pbq[u] = PBb[tn];

                if (t < len) {
                    const double pb = (double)pbf;
                    const double p0 = (double)__uint_as_float((unsigned)gu.x << 16);
                    const double p1 = (double)__uint_as_float((unsigned)gu.y << 16);
                    const double p2 = (double)__uint_as_float((unsigned)gu.z << 16);
                    const double p3 = (double)__uint_as_float((unsigned)gu.w << 16);

                    const double l7 = dpp_shr1_zero_f64(a7);

                    const double n0 = (a0 + l7) * pb;
                    const double n1 = fma(m1d, l7, a1 + a0) * p0;
                    const double n2 = (a2 + a1) * pb;
                    const double n3 = fma(m3d, a1, a3 + a2) * p1;
                    const double n4 = (a4 + a3) * pb;
                    const double n5 = fma(m5d, a3, a5 + a4) * p2;
                    const double n6 = (a6 + a5) * pb;
                    const double n7 = fma(m7d, a5, a7 + a6) * p3;
                    const double n8 = (a8 + a7) * pb;

                    a0 = n0; a1 = n1; a2 = n2; a3 = n3; a4 = n4;
                    a5 = n5; a6 = n6; a7 = n7; a8 = n8;
                }

                if (u == 7 || u == 15 || u == 23) {
                    double m = fmax(a0, a1);
                    m = fmax(m, a2); m = fmax(m, a3); m = fmax(m, a4);
                    m = fmax(m, a5); m = fmax(m, a6); m = fmax(m, a7);
                    m = fmax(m, a8);
                    int Eb = (__double2hiint(m) >> 20) & 0x7ff;
                    int Ex = wave_imax_dpp(Eb);
                    if (Ex < 1) Ex = 1;
                    const double inv = __hiloint2double((2046 - Ex) << 20, 0);
                    Ksum += (long long)(Ex - 1023);
                    a0 *= inv; a1 *= inv; a2 *= inv; a3 *= inv; a4 *= inv;
                    a5 *= inv; a6 *= inv; a7 *= inv; a8 *= inv;
                }
            }
        }

        smd[lane * 8 + 0] = a0; smd[lane * 8 + 1] = a1;
        smd[lane * 8 + 2] = a2; smd[lane * 8 + 3] = a3;
        smd[lane * 8 + 4] = a4; smd[lane * 8 + 5] = a5;
        smd[lane * 8 + 6] = a6; smd[lane * 8 + 7] = a7;
        if (lane == 63) smd[512] = a8;
        __syncthreads();
        if (lane == 0) {
            const int l = 2 * tl + 1;
            const double s = smd[l - 1] + smd[l - 2];
            const double ll = (double)Ksum * 0.6931471805599453 + log(s);
            ctc_out[b] = (float)(-ll / (double)tl);
        }
    } else {
        // --------------------- SoftDTW, hard-min wavefront ---------------------
        const int b = bid - NB;
        const float* Db = Ddiag + (size_t)b * NDG * NS;

        float rp10 = BIGV, rp11 = BIGV, rp12 = BIGV, rp13 = BIGV;
        float rp20 = BIGV, rp21 = BIGV, rp22 = BIGV, rp23 = BIGV;
        if (lane == 0) rp10 = Db[0];

        float4 dq[32];
        #pragma unroll
        for (int q = 0; q < 32; ++q)
            dq[q] = ((const float4*)(Db + (size_t)(1 + q) * NS))[lane];

        float res = 0.f;
        for (int d0 = 1; d0 < 1279; d0 += 32) {
            #pragma unroll
            for (int u = 0; u < 32; ++u) {
                const int d = d0 + u;
                const float4 Dv = dq[u];
                int dn = d + 32; if (dn > NDG - 1) dn = NDG - 1;
                dq[u] = ((const float4*)(Db + (size_t)dn * NS))[lane];

                const float lf1 = dpp_shr1_f32(rp13, BIGV);
                const float lf2 = dpp_shr1_f32(rp23, BIGV);

                const float c0 = Dv.x + fminf(fminf(rp10, lf1),  lf2);
                const float c1 = Dv.y + fminf(fminf(rp11, rp10), rp20);
                const float c2 = Dv.z + fminf(fminf(rp12, rp11), rp21);
                const float c3 = Dv.w + fminf(fminf(rp13, rp12), rp22);

                rp20 = rp10; rp21 = rp11; rp22 = rp12; rp23 = rp13;
                rp10 = c0;   rp11 = c1;   rp12 = c2;   rp13 = c3;

                res = (d == NDG - 1) ? c3 : res;
            }
        }
        if (lane == 63) sdtw_out[b] = res;
    }
}

// ---------------------------------------------------------------------------
// K3: final scalar = mean(ctc) + mean(sdtw)
// ---------------------------------------------------------------------------
__global__ __launch_bounds__(64) void k_final(
    const float* __restrict__ ctc_out, const float* __restrict__ sdtw_out,
    float* __restrict__ out)
{
    int lane = threadIdx.x;
    float c = ctc_out[lane];
    float s = sdtw_out[lane];
    #pragma unroll
    for (int off = 32; off > 0; off >>= 1) {
        c += __shfl_down(c, off);
        s += __shfl_down(s, off);
    }
    if (lane == 0) out[0] = c / 64.f + s / 64.f;
}

extern "C" void kernel_launch(void* const* d_in, const int* in_sizes, int n_in,
                              void* d_out, int out_size, void* d_ws, size_t ws_size,
                              hipStream_t stream) {
    const float* lp   = (const float*)d_in[0];
    const float* fm   = (const float*)d_in[1];
    const int*   tgt  = (const int*)d_in[2];
    const int*   ilen = (const int*)d_in[3];
    const int*   tlen = (const int*)d_in[4];
    float* out = (float*)d_out;

    // ws layout: Ddiag (83.56 MB) | Gbf bf16 (32 MB) | PB (256 KB) | results
    char* ws = (char*)d_ws;
    float* Ddiag = (float*)ws;
    size_t dbytes = (size_t)NB * NDG * NS * sizeof(float);          // 83,820,544
    unsigned short* Gbf = (unsigned short*)(ws + dbytes);
    size_t gbytes = (size_t)NB * NT * NS * sizeof(unsigned short);  // 33,554,432
    float* PB = (float*)(ws + dbytes + gbytes);
    size_t pbytes = (size_t)NB * NT * sizeof(float);                // 262,144
    float* ctc_res  = (float*)(ws + dbytes + gbytes + pbytes);
    float* sdtw_res = ctc_res + 64;

    hipLaunchKernelGGL(k_dmat, dim3(NB * 8), dim3(256), 0, stream,
                       lp, fm, tgt, Ddiag, Gbf, PB);
    hipLaunchKernelGGL(k_dp, dim3(2 * NB), dim3(64), 0, stream,
                       lp, tgt, ilen, tlen, Ddiag, Gbf, PB, ctc_res, sdtw_res);
    hipLaunchKernelGGL(k_final, dim3(1), dim3(64), 0, stream, ctc_res, sdtw_res, out);
}

// Round 9
// 260.356 us; speedup vs baseline: 1.1334x; 1.1334x over previous
//
#include <hip/hip_runtime.h>
#include <math.h>

// Problem constants (fixed by setup_inputs)
constexpr int NB = 64;     // batch
constexpr int NT = 1024;   // time steps
constexpr int NV = 256;    // vocab
constexpr int NS = 256;    // target length (padded)
constexpr int NL = 2 * NS + 1;        // 513 extended CTC states
constexpr int NDG = NT + NS - 1;      // 1279 anti-diagonals
__device__ constexpr float BIGV = 1e10f;

using f32x4 = __attribute__((ext_vector_type(4))) float;
using s16x8 = __attribute__((ext_vector_type(8))) short;

// ---------------- DPP cross-lane helpers ----------------
__device__ __forceinline__ float dpp_shr1_f32(float x, float lane0val) {
    int r = __builtin_amdgcn_update_dpp(__float_as_int(lane0val),
                                        __float_as_int(x), 0x138, 0xf, 0xf, false);
    return __int_as_float(r);
}
__device__ __forceinline__ double dpp_shr1_zero_f64(double x) {
    union { double d; unsigned long long u; } c; c.d = x;
    int lo = (int)(c.u & 0xffffffffull), hi = (int)(c.u >> 32);
    int nlo = __builtin_amdgcn_update_dpp(0, lo, 0x138, 0xf, 0xf, true);
    int nhi = __builtin_amdgcn_update_dpp(0, hi, 0x138, 0xf, 0xf, true);
    c.u = ((unsigned long long)(unsigned)nhi << 32) | (unsigned)nlo;
    return c.d;
}
__device__ __forceinline__ int wave_imax_dpp(int x) {   // non-negative x
    int t;
    t = __builtin_amdgcn_update_dpp(0, x, 0x111, 0xf, 0xf, true); x = max(x, t);
    t = __builtin_amdgcn_update_dpp(0, x, 0x112, 0xf, 0xf, true); x = max(x, t);
    t = __builtin_amdgcn_update_dpp(0, x, 0x114, 0xf, 0xf, true); x = max(x, t);
    t = __builtin_amdgcn_update_dpp(0, x, 0x118, 0xf, 0xf, true); x = max(x, t);
    t = __builtin_amdgcn_update_dpp(0, x, 0x142, 0xf, 0xf, true); x = max(x, t);
    t = __builtin_amdgcn_update_dpp(0, x, 0x143, 0xf, 0xf, true); x = max(x, t);
    return __builtin_amdgcn_readlane(x, 63);
}
__device__ __forceinline__ float row16_sum(float x) {
    x += __int_as_float(__builtin_amdgcn_update_dpp(0, __float_as_int(x), 0x111, 0xf, 0xf, true));
    x += __int_as_float(__builtin_amdgcn_update_dpp(0, __float_as_int(x), 0x112, 0xf, 0xf, true));
    x += __int_as_float(__builtin_amdgcn_update_dpp(0, __float_as_int(x), 0x114, 0xf, 0xf, true));
    x += __int_as_float(__builtin_amdgcn_update_dpp(0, __float_as_int(x), 0x118, 0xf, 0xf, true));
    return x;
}
__device__ __forceinline__ unsigned short f2bf(float x) {   // round-to-nearest-even
    unsigned u = __float_as_uint(x);
    return (unsigned short)((u + 0x7fffu + ((u >> 16) & 1u)) >> 16);
}
__device__ __forceinline__ float bf2f(unsigned short h) {
    return __uint_as_float((unsigned)h << 16);
}

// ---------------------------------------------------------------------------
// K1 (MFMA): per block = 128 rows of one batch. Ddiag stored as BF16.
// ---------------------------------------------------------------------------
__global__ __launch_bounds__(256) void k_dmat(
    const float* __restrict__ lp, const float* __restrict__ fm,
    const int* __restrict__ tgt, unsigned short* __restrict__ Ddiag,
    unsigned short* __restrict__ Gbf, float* __restrict__ PB)
{
    constexpr int ESTR = 264;
    constexpr int FSTR = 264;
    constexpr int TSTR = 40;
    constexpr int PSTR = 40;
    constexpr int DSTR = 130;

    __shared__ __align__(16) unsigned char uni[128 * ESTR * 2];  // E / Dst union
    __shared__ __align__(16) unsigned short FT[32 * FSTR];
    __shared__ __align__(16) unsigned short tgf[256 * TSTR];
    __shared__ __align__(16) unsigned short pb16[128 * PSTR];
    __shared__ float tsq[256];
    __shared__ float psq[128];

    unsigned short* E = (unsigned short*)uni;
    float* Dst = (float*)uni;

    const int tid  = threadIdx.x;
    const int lane = tid & 63;
    const int w    = tid >> 6;
    const int b    = blockIdx.x >> 3;
    const int a0   = (blockIdx.x & 7) * 128;

    {
        const float* fr = fm + tid * 24;
        #pragma unroll
        for (int k = 0; k < 24; k += 4) {
            float4 t4 = *(const float4*)(fr + k);
            FT[(k + 0) * FSTR + tid] = f2bf(t4.x);
            FT[(k + 1) * FSTR + tid] = f2bf(t4.y);
            FT[(k + 2) * FSTR + tid] = f2bf(t4.z);
            FT[(k + 3) * FSTR + tid] = f2bf(t4.w);
        }
        #pragma unroll
        for (int n = 24; n < 32; ++n) FT[n * FSTR + tid] = 0;
    }
    const int lab = tgt[b * NS + tid];
    {
        const float* fr = fm + lab * 24;
        float s = 0.f;
        #pragma unroll
        for (int k = 0; k < 24; k += 4) {
            float4 t4 = *(const float4*)(fr + k);
            unsigned p0 = f2bf(t4.x) | ((unsigned)f2bf(t4.y) << 16);
            unsigned p1 = f2bf(t4.z) | ((unsigned)f2bf(t4.w) << 16);
            *(unsigned*)&tgf[tid * TSTR + k]     = p0;
            *(unsigned*)&tgf[tid * TSTR + k + 2] = p1;
            s += t4.x * t4.x + t4.y * t4.y + t4.z * t4.z + t4.w * t4.w;
        }
        #pragma unroll
        for (int k = 24; k < 32; k += 2) *(unsigned*)&tgf[tid * TSTR + k] = 0;
        tsq[tid] = s;
    }
    {
        const float* src = lp + ((size_t)b * NT + a0) * NV;
        #pragma unroll
        for (int it = 0; it < 32; ++it) {
            int f4  = it * 256 + tid;
            int row = f4 >> 6;
            int c4  = f4 & 63;
            float4 v = *(const float4*)(src + row * NV + c4 * 4);
            float e0 = __expf(v.x), e1 = __expf(v.y);
            float e2 = __expf(v.z), e3 = __expf(v.w);
            unsigned* dst = (unsigned*)&E[row * ESTR + c4 * 4];
            dst[0] = f2bf(e0) | ((unsigned)f2bf(e1) << 16);
            dst[1] = f2bf(e2) | ((unsigned)f2bf(e3) << 16);
            if (c4 == 0) PB[b * NT + a0 + row] = e0;
        }
    }
    __syncthreads();

    {
        unsigned short* gd = Gbf + (((size_t)(b * NT + a0)) << 8) + tid;
        #pragma unroll 4
        for (int r = 0; r < 128; ++r) gd[(size_t)r << 8] = E[r * ESTR + lab];
    }

    const int m0  = 32 * w;
    const int q   = lane >> 4;
    const int n16 = lane & 15;
    f32x4 acc00 = {0.f, 0.f, 0.f, 0.f}, acc01 = acc00, acc10 = acc00, acc11 = acc00;
    #pragma unroll
    for (int ks = 0; ks < 8; ++ks) {
        s16x8 a0f = *(const s16x8*)&E[(m0 + n16) * ESTR + ks * 32 + q * 8];
        s16x8 a1f = *(const s16x8*)&E[(m0 + 16 + n16) * ESTR + ks * 32 + q * 8];
        s16x8 b0f = *(const s16x8*)&FT[(n16) * FSTR + ks * 32 + q * 8];
        s16x8 b1f = *(const s16x8*)&FT[(16 + n16) * FSTR + ks * 32 + q * 8];
        acc00 = __builtin_amdgcn_mfma_f32_16x16x32_bf16(a0f, b0f, acc00, 0, 0, 0);
        acc01 = __builtin_amdgcn_mfma_f32_16x16x32_bf16(a0f, b1f, acc01, 0, 0, 0);
        acc10 = __builtin_amdgcn_mfma_f32_16x16x32_bf16(a1f, b0f, acc10, 0, 0, 0);
        acc11 = __builtin_amdgcn_mfma_f32_16x16x32_bf16(a1f, b1f, acc11, 0, 0, 0);
    }
    #pragma unroll
    for (int r = 0; r < 4; ++r) {
        float s0 = acc00[r] * acc00[r] + acc01[r] * acc01[r];
        float s1 = acc10[r] * acc10[r] + acc11[r] * acc11[r];
        s0 = row16_sum(s0); s1 = row16_sum(s1);
        if (n16 == 15) {
            psq[m0 + 4 * q + r]      = s0;
            psq[m0 + 16 + 4 * q + r] = s1;
        }
        pb16[(m0 + 4 * q + r) * PSTR + n16]           = f2bf(acc00[r]);
        pb16[(m0 + 4 * q + r) * PSTR + 16 + n16]      = f2bf(acc01[r]);
        pb16[(m0 + 16 + 4 * q + r) * PSTR + n16]      = f2bf(acc10[r]);
        pb16[(m0 + 16 + 4 * q + r) * PSTR + 16 + n16] = f2bf(acc11[r]);
    }

    #pragma unroll 1
    for (int h = 0; h < 2; ++h) {
        __syncthreads();
        s16x8 pa0 = *(const s16x8*)&pb16[(m0 + n16) * PSTR + q * 8];
        s16x8 pa1 = *(const s16x8*)&pb16[(m0 + 16 + n16) * PSTR + q * 8];
        float ps0[4], ps1[4];
        #pragma unroll
        for (int r = 0; r < 4; ++r) {
            ps0[r] = psq[m0 + 4 * q + r];
            ps1[r] = psq[m0 + 16 + 4 * q + r];
        }
        #pragma unroll
        for (int nt = 0; nt < 8; ++nt) {
            const int j0 = 16 * nt;
            s16x8 tb = *(const s16x8*)&tgf[(128 * h + j0 + n16) * TSTR + q * 8];
            float tq = tsq[128 * h + j0 + n16];
            f32x4 z = {0.f, 0.f, 0.f, 0.f};
            f32x4 d0 = __builtin_amdgcn_mfma_f32_16x16x32_bf16(pa0, tb, z, 0, 0, 0);
            f32x4 d1 = __builtin_amdgcn_mfma_f32_16x16x32_bf16(pa1, tb, z, 0, 0, 0);
            #pragma unroll
            for (int r = 0; r < 4; ++r) {
                Dst[(m0 + 4 * q + r) * DSTR + j0 + n16]      = ps0[r] + tq - 2.f * d0[r];
                Dst[(m0 + 16 + 4 * q + r) * DSTR + j0 + n16] = ps1[r] + tq - 2.f * d1[r];
            }
        }
        __syncthreads();
        for (int i = 0; i < 64; ++i) {
            int dp  = 4 * i + w;
            int jlo = dp > 127 ? dp - 127 : 0;
            int jhi = dp < 127 ? dp : 127;
            #pragma unroll
            for (int c = 0; c < 2; ++c) {
                int jj = jlo + 64 * c + lane;
                if (jj <= jhi) {
                    unsigned short vv = f2bf(Dst[(dp - jj) * DSTR + jj]);
                    Ddiag[((size_t)b * NDG + a0 + 128 * h + dp) * NS + 128 * h + jj] = vv;
                }
            }
        }
    }
}

// ---------------------------------------------------------------------------
// K2: single-wave DPs; DPP cross-lane; branch-free load streams.
// blocks 0..63:  CTC linear-FP64 (R6/R7-verified numerics), depth-16 queue,
//                full-group/remainder loop split, pow-2 rescale every 8 steps.
// blocks 64..127: SoftDTW hard-min wavefront, bf16 cost reads, depth-16 queue.
// ---------------------------------------------------------------------------
__global__ __launch_bounds__(64) void k_dp(
    const float* __restrict__ lp, const int* __restrict__ tgt,
    const int* __restrict__ ilen, const int* __restrict__ tlen,
    const unsigned short* __restrict__ Ddiag, const unsigned short* __restrict__ Gbf,
    const float* __restrict__ PB, float* __restrict__ ctc_out,
    float* __restrict__ sdtw_out)
{
    __shared__ double smd[513];
    const int lane = threadIdx.x;
    const int bid = blockIdx.x;

    if (bid < NB) {
        // ------------------------- CTC, linear fp64 -------------------------
        const int b  = bid;
        const int len = ilen[b];          // wave-uniform (768..1024)
        const int tl  = tlen[b];
        const float* lpb = lp + (size_t)b * NT * NV;
        const unsigned short* Gb = Gbf + ((size_t)(b * NT) << 8);
        const float* PBb = PB + b * NT;

        const int4 t4 = ((const int4*)(tgt + b * NS))[lane];
        const int prevw = __shfl_up(t4.w, 1);
        const double m1d = ((lane > 0) && (t4.x != prevw)) ? 1.0 : 0.0;
        const double m3d = (t4.y != t4.x) ? 1.0 : 0.0;
        const double m5d = (t4.z != t4.y) ? 1.0 : 0.0;
        const double m7d = (t4.w != t4.z) ? 1.0 : 0.0;

        double a0 = 0.0, a1 = 0.0, a2 = 0.0, a3 = 0.0, a4 = 0.0,
               a5 = 0.0, a6 = 0.0, a7 = 0.0, a8 = 0.0;
        if (lane == 0) {
            a0 = (double)__expf(lpb[0]);
            a1 = (double)__expf(lpb[t4.x]);
        }
        long long Ksum = 0;

        auto ctc_step = [&](const ushort4 gu, const float pbf) {
            const double pb = (double)pbf;
            const double p0 = (double)bf2f(gu.x), p1 = (double)bf2f(gu.y);
            const double p2 = (double)bf2f(gu.z), p3 = (double)bf2f(gu.w);
            const double l7 = dpp_shr1_zero_f64(a7);
            const double n0 = (a0 + l7) * pb;
            const double n1 = fma(m1d, l7, a1 + a0) * p0;
            const double n2 = (a2 + a1) * pb;
            const double n3 = fma(m3d, a1, a3 + a2) * p1;
            const double n4 = (a4 + a3) * pb;
            const double n5 = fma(m5d, a3, a5 + a4) * p2;
            const double n6 = (a6 + a5) * pb;
            const double n7 = fma(m7d, a5, a7 + a6) * p3;
            const double n8 = (a8 + a7) * pb;
            a0 = n0; a1 = n1; a2 = n2; a3 = n3; a4 = n4;
            a5 = n5; a6 = n6; a7 = n7; a8 = n8;
        };
        auto ctc_rescale = [&]() {
            double m = fmax(a0, a1);
            m = fmax(m, a2); m = fmax(m, a3); m = fmax(m, a4);
            m = fmax(m, a5); m = fmax(m, a6); m = fmax(m, a7);
            m = fmax(m, a8);
            int Eb = (__double2hiint(m) >> 20) & 0x7ff;
            int Ex = wave_imax_dpp(Eb);
            if (Ex < 1) Ex = 1;
            const double inv = __hiloint2double((2046 - Ex) << 20, 0); // 2^(1023-Ex)
            Ksum += (long long)(Ex - 1023);
            a0 *= inv; a1 *= inv; a2 *= inv; a3 *= inv; a4 *= inv;
            a5 *= inv; a6 *= inv; a7 *= inv; a8 *= inv;
        };

        ushort4 gq[16];
        float   pbq[16];
        #pragma unroll
        for (int q = 0; q < 16; ++q) {
            gq[q]  = *(const ushort4*)(Gb + (((size_t)(1 + q)) << 8) + 4 * lane);
            pbq[q] = PBb[1 + q];
        }

        int t0 = 1;
        for (; t0 + 16 <= len; t0 += 16) {      // full groups: no per-step branch
            #pragma unroll
            for (int u = 0; u < 16; ++u) {
                const int t = t0 + u;
                const ushort4 gu = gq[u];
                const float pbf  = pbq[u];
                int tn = t + 16; if (tn > NT - 1) tn = NT - 1;
                gq[u]  = *(const ushort4*)(Gb + (((size_t)tn) << 8) + 4 * lane);
                pbq[u] = PBb[tn];
                ctc_step(gu, pbf);
                if (u == 7 || u == 15) ctc_rescale();
            }
        }
        {   // remainder (< 16 steps), consume-only
            #pragma unroll
            for (int u = 0; u < 16; ++u) {
                if (t0 + u < len) ctc_step(gq[u], pbq[u]);
                if (u == 7) ctc_rescale();
            }
        }

        smd[lane * 8 + 0] = a0; smd[lane * 8 + 1] = a1;
        smd[lane * 8 + 2] = a2; smd[lane * 8 + 3] = a3;
        smd[lane * 8 + 4] = a4; smd[lane * 8 + 5] = a5;
        smd[lane * 8 + 6] = a6; smd[lane * 8 + 7] = a7;
        if (lane == 63) smd[512] = a8;
        __syncthreads();
        if (lane == 0) {
            const int l = 2 * tl + 1;
            const double s = smd[l - 1] + smd[l - 2];
            const double ll = (double)Ksum * 0.6931471805599453 + log(s);
            ctc_out[b] = (float)(-ll / (double)tl);
        }
    } else {
        // ------------- SoftDTW, hard-min wavefront, bf16 costs -------------
        const int b = bid - NB;
        const unsigned short* Db = Ddiag + (size_t)b * NDG * NS;

        float rp10 = BIGV, rp11 = BIGV, rp12 = BIGV, rp13 = BIGV;
        float rp20 = BIGV, rp21 = BIGV, rp22 = BIGV, rp23 = BIGV;
        if (lane == 0) rp10 = bf2f(Db[0]);

        ushort4 dq[16];
        #pragma unroll
        for (int q = 0; q < 16; ++q)
            dq[q] = *(const ushort4*)(Db + (size_t)(1 + q) * NS + 4 * lane);

        float res = 0.f;
        for (int d0 = 1; d0 < 1281; d0 += 16) {
            #pragma unroll
            for (int u = 0; u < 16; ++u) {
                const int d = d0 + u;
                const ushort4 Dv = dq[u];
                int dn = d + 16; if (dn > NDG - 1) dn = NDG - 1;
                dq[u] = *(const ushort4*)(Db + (size_t)dn * NS + 4 * lane);

                const float Dx = bf2f(Dv.x), Dy = bf2f(Dv.y);
                const float Dz = bf2f(Dv.z), Dw = bf2f(Dv.w);

                const float lf1 = dpp_shr1_f32(rp13, BIGV);
                const float lf2 = dpp_shr1_f32(rp23, BIGV);

                const float c0 = Dx + fminf(fminf(rp10, lf1),  lf2);
                const float c1 = Dy + fminf(fminf(rp11, rp10), rp20);
                const float c2 = Dz + fminf(fminf(rp12, rp11), rp21);
                const float c3 = Dw + fminf(fminf(rp13, rp12), rp22);

                rp20 = rp10; rp21 = rp11; rp22 = rp12; rp23 = rp13;
                rp10 = c0;   rp11 = c1;   rp12 = c2;   rp13 = c3;

                res = (d == NDG - 1) ? c3 : res;
            }
        }
        if (lane == 63) sdtw_out[b] = res;
    }
}

// ---------------------------------------------------------------------------
// K3: final scalar = mean(ctc) + mean(sdtw)
// ---------------------------------------------------------------------------
__global__ __launch_bounds__(64) void k_final(
    const float* __restrict__ ctc_out, const float* __restrict__ sdtw_out,
    float* __restrict__ out)
{
    int lane = threadIdx.x;
    float c = ctc_out[lane];
    float s = sdtw_out[lane];
    #pragma unroll
    for (int off = 32; off > 0; off >>= 1) {
        c += __shfl_down(c, off);
        s += __shfl_down(s, off);
    }
    if (lane == 0) out[0] = c / 64.f + s / 64.f;
}

extern "C" void kernel_launch(void* const* d_in, const int* in_sizes, int n_in,
                              void* d_out, int out_size, void* d_ws, size_t ws_size,
                              hipStream_t stream) {
    const float* lp   = (const float*)d_in[0];
    const float* fm   = (const float*)d_in[1];
    const int*   tgt  = (const int*)d_in[2];
    const int*   ilen = (const int*)d_in[3];
    const int*   tlen = (const int*)d_in[4];
    float* out = (float*)d_out;

    // ws layout: Ddiag bf16 (41.9 MB) | Gbf bf16 (32 MB) | PB (256 KB) | results
    char* ws = (char*)d_ws;
    unsigned short* Ddiag = (unsigned short*)ws;
    size_t dbytes = (size_t)NB * NDG * NS * sizeof(unsigned short); // 41,910,272
    unsigned short* Gbf = (unsigned short*)(ws + dbytes);
    size_t gbytes = (size_t)NB * NT * NS * sizeof(unsigned short);  // 33,554,432
    float* PB = (float*)(ws + dbytes + gbytes);
    size_t pbytes = (size_t)NB * NT * sizeof(float);                // 262,144
    float* ctc_res  = (float*)(ws + dbytes + gbytes + pbytes);
    float* sdtw_res = ctc_res + 64;

    hipLaunchKernelGGL(k_dmat, dim3(NB * 8), dim3(256), 0, stream,
                       lp, fm, tgt, Ddiag, Gbf, PB);
    hipLaunchKernelGGL(k_dp, dim3(2 * NB), dim3(64), 0, stream,
                       lp, tgt, ilen, tlen, Ddiag, Gbf, PB, ctc_res, sdtw_res);
    hipLaunchKernelGGL(k_final, dim3(1), dim3(64), 0, stream, ctc_res, sdtw_res, out);
}